// Round 12
// baseline (348.541 us; speedup 1.0000x reference)
//
#include <hip/hip_runtime.h>
#include <hip/hip_bf16.h>

typedef unsigned short u16;
typedef unsigned int u32;
typedef __attribute__((ext_vector_type(8))) short short8_v;   // 8 bf16 (4 VGPRs)
typedef __attribute__((ext_vector_type(4))) float float4_v;

__device__ __forceinline__ u16 f2bf(float f) {
  u32 u = __float_as_uint(f);
  return (u16)((u + 0x7fffu + ((u >> 16) & 1u)) >> 16);   // RNE
}

__device__ __forceinline__ void gl_lds16(const void* g, void* l) {
  __builtin_amdgcn_global_load_lds(
      (const __attribute__((address_space(1))) u32*)g,
      (__attribute__((address_space(3))) u32*)l, 16, 0, 0);
}

// stage 1024 16B units (4 per thread), inverse-swizzled global source, linear LDS dest
__device__ __forceinline__ void stage_tile_1024(const char* src, char* dst, int wid, int lane) {
  const int u0 = wid * 256;
  #pragma unroll
  for (int i = 0; i < 4; ++i) {
    int u = u0 + i * 64 + lane;
    int cl = u >> 2;
    int qs = (u & 3) ^ ((u >> 3) & 3);
    gl_lds16(src + (size_t)cl * 512 + qs * 16, dst + (size_t)(u0 + i * 64) * 16);
  }
}
__device__ __forceinline__ void stage_tile_B(const char* src, char* dst, int wid, int lane) {
  stage_tile_1024(src, dst, wid, lane);
  if (wid == 0) {   // rows 256..271 (64 extra units)
    int u = 1024 + lane;
    int du = u >> 2;
    int qs = (u & 3) ^ ((u >> 3) & 3);
    gl_lds16(src + (size_t)du * 512 + qs * 16, dst + (size_t)1024 * 16);
  }
}

// ---------------- gate (wave-parallel, 1 wave per sample) + fold + loss ----------------
__global__ void gate_fold_kernel(const float* __restrict__ meta,
                                 const float* __restrict__ gw1, const float* __restrict__ gb1,
                                 const float* __restrict__ gw2, const float* __restrict__ gb2,
                                 const float* __restrict__ c1b, const float* __restrict__ g1,
                                 const float* __restrict__ be1, const float* __restrict__ m1,
                                 const float* __restrict__ v1,
                                 const float* __restrict__ c2b, const float* __restrict__ g2,
                                 const float* __restrict__ be2, const float* __restrict__ m2,
                                 const float* __restrict__ v2,
                                 float* __restrict__ fold1, float* __restrict__ fold2,
                                 int* __restrict__ top1, float* __restrict__ loss_out) {
  const int tid = threadIdx.x;   // 1024
  __shared__ float probs[16][6];

  for (int t = tid; t < 3072; t += 1024) {
    int conv = t >= 1536 ? 1 : 0;
    int r = t - (conv ? 1536 : 0);
    if (conv == 0) {
      float scale = g1[r] * rsqrtf(v1[r] + 1e-5f);
      float shift = (c1b[r] - m1[r]) * scale + be1[r];
      fold1[r * 2] = scale; fold1[r * 2 + 1] = shift;
    } else {
      float scale = g2[r] * rsqrtf(v2[r] + 1e-5f);
      float shift = (c2b[r] - m2[r]) * scale + be2[r];
      fold2[r * 2] = scale; fold2[r * 2 + 1] = shift;
    }
  }

  const int b = tid >> 6, lane = tid & 63;
  float h0 = gb1[lane], h1 = gb1[lane + 64];
  #pragma unroll
  for (int i = 0; i < 9; ++i) {
    float m = meta[b * 9 + i];
    h0 += m * gw1[i * 128 + lane];
    h1 += m * gw1[i * 128 + lane + 64];
  }
  h0 = fmaxf(h0, 0.f); h1 = fmaxf(h1, 0.f);
  float v[6];
  #pragma unroll
  for (int k = 0; k < 6; ++k)
    v[k] = h0 * gw2[lane * 6 + k] + h1 * gw2[(lane + 64) * 6 + k];
  #pragma unroll
  for (int off = 32; off >= 1; off >>= 1)
    #pragma unroll
    for (int k = 0; k < 6; ++k) v[k] += __shfl_xor(v[k], off, 64);
  if (lane == 0) {
    float lg[6];
    #pragma unroll
    for (int k = 0; k < 6; ++k) lg[k] = v[k] + gb2[k];
    float m = lg[0];
    for (int k = 1; k < 6; ++k) m = fmaxf(m, lg[k]);
    float s = 0.f, p[6];
    for (int k = 0; k < 6; ++k) { p[k] = expf(lg[k] - m); s += p[k]; }
    int best = 0; float bm = p[0];
    for (int k = 1; k < 6; ++k) if (p[k] > bm) { bm = p[k]; best = k; }
    top1[b] = best;
    for (int k = 0; k < 6; ++k) probs[b][k] = p[k] / s;
  }
  __syncthreads();
  if (tid == 0) {
    float col[6] = {0, 0, 0, 0, 0, 0}, tot = 0.f;
    for (int bb = 0; bb < 16; ++bb)
      for (int k = 0; k < 6; ++k) col[k] += probs[bb][k];
    for (int k = 0; k < 6; ++k) tot += col[k];
    float imp[6], mean = 0.f;
    for (int k = 0; k < 6; ++k) { imp[k] = col[k] / (tot + 1e-8f); mean += imp[k]; }
    mean *= (1.f / 6.f);
    float var = 0.f;
    for (int k = 0; k < 6; ++k) { float d = imp[k] - mean; var += d * d; }
    loss_out[0] = sqrtf(var * 0.2f);   // ddof=1 -> /5
  }
}

// ---- unified prep: [0,3072) wprep | [3072,4096) transpose | [4096,5136) border zero ----
__global__ void prep_kernel(const float* __restrict__ w1, const float* __restrict__ w2,
                            u16* __restrict__ w1t, u16* __restrict__ w2t,
                            const float* __restrict__ x, u16* __restrict__ xpt,
                            u16* __restrict__ hpt) {
  const int tid = threadIdx.x;   // 256
  __shared__ u16 tile[64 * 258];  // 33,024 B; aliased as float buf[2304] by wprep branch
  const int bx = blockIdx.x;

  if (bx < 3072) {
    // weights: [E][co][ci][3][3] f32 -> [E][tap][co][ci] bf16
    float* buf = (float*)tile;
    const int conv = bx >= 1536 ? 1 : 0;
    const int r = bx - (conv ? 1536 : 0);   // e*256 + co
    const int e = r >> 8, co = r & 255;
    const float* src = (conv ? w2 : w1) + (size_t)r * 2304;
    u16* wdst = conv ? w2t : w1t;
    const float4* s4 = (const float4*)src;
    for (int k = tid; k < 576; k += 256) ((float4*)buf)[k] = s4[k];
    __syncthreads();
    for (int j = tid; j < 288; j += 256) {
      int tap = j >> 5, ci0 = (j & 31) * 8;
      u16 v[8];
      #pragma unroll
      for (int i = 0; i < 8; ++i) v[i] = f2bf(buf[(ci0 + i) * 9 + tap]);
      int4 pk;
      pk.x = (int)((u32)v[0] | ((u32)v[1] << 16));
      pk.y = (int)((u32)v[2] | ((u32)v[3] << 16));
      pk.z = (int)((u32)v[4] | ((u32)v[5] << 16));
      pk.w = (int)((u32)v[6] | ((u32)v[7] << 16));
      *(int4*)(wdst + (((size_t)e * 9 + tap) * 256 + co) * 256 + ci0) = pk;
    }
    return;
  }
  if (bx >= 4096) {
    // border zero: 2 bufs x 16 b x 260 rc-rows x 32 parts
    int t = (bx - 4096) * 256 + tid;
    int buf = t / (16 * 260 * 32);
    int r = t % (16 * 260 * 32);
    int b = r / (260 * 32);
    int r2 = r % (260 * 32);
    int idx = r2 >> 5, part = r2 & 31;
    int rc;
    if (idx < 66) rc = idx;
    else if (idx < 132) rc = 65 * 66 + (idx - 66);
    else { int rem = idx - 132; rc = (1 + (rem >> 1)) * 66 + (rem & 1) * 65; }
    u16* base = buf ? hpt : xpt;
    int4 z = {0, 0, 0, 0};
    *(int4*)(base + ((size_t)b * 4356 + rc) * 256 + part * 8) = z;
    return;
  }
  // input NCHW f32 -> padded [b][rc=66*66][ci=256] bf16 (interior)
  const int blk = bx - 3072;
  const int b = blk >> 6, r = blk & 63;
  const int cg = tid & 15, ci_g = tid >> 4;
  const float4* xb4 = (const float4*)(x + ((size_t)b * 256) * 4096 + r * 64);
  #pragma unroll
  for (int k = 0; k < 16; ++k) {
    int ci = k * 16 + ci_g;
    float4 v = xb4[(size_t)ci * 1024 + cg];
    tile[(cg * 4 + 0) * 258 + ci] = f2bf(v.x);
    tile[(cg * 4 + 1) * 258 + ci] = f2bf(v.y);
    tile[(cg * 4 + 2) * 258 + ci] = f2bf(v.z);
    tile[(cg * 4 + 3) * 258 + ci] = f2bf(v.w);
  }
  __syncthreads();
  u16* dstb = xpt + ((size_t)b * 4356 + (size_t)(r + 1) * 66 + 1) * 256;
  #pragma unroll
  for (int it = 0; it < 8; ++it) {
    int chunk = it * 256 + tid;
    int cc = chunk >> 5, part = chunk & 31;
    const u32* lp = (const u32*)(tile + cc * 258 + part * 8);
    int4 vv = {(int)lp[0], (int)lp[1], (int)lp[2], (int)lp[3]};
    *(int4*)(dstb + (size_t)cc * 256 + part * 8) = vv;
  }
}

// ---------------- conv3x3 + BN + ReLU as implicit GEMM (MFMA bf16) ----------------
// 2-deep pipeline with RAW barrier + vmcnt AFTER the MFMA cluster (T4-style):
//   step i: issue prefetch_{i+1} -> buf[cur^1]; ds_read buf[cur] -> regs;
//           MFMA x32; asm vmcnt(0); s_barrier.
// Own-loads-then-barrier => all waves' loads landed before any wave reads (same
// load sequence per wave). Prefetch targets a buffer whose readers all finished
// before the PREVIOUS barrier => no overwrite race. Stage latency hides under MFMA.
// Tile: 256co x 128pix, 4 waves (2x2), wave tile 128x64, acc[8][4], 32 MFMA/step.
// Grid 512 flat, bijective XCD swizzle. LDS 16B-slot swizzle slot=q^((row>>1)&3),
// inverse-applied at global source (linear LDS dest) and at ds_read (rule #21).
template <int MODE>
__global__ __launch_bounds__(256, 2) void conv_mfma_kernel(
    const u16* __restrict__ src, const u16* __restrict__ wt,
    const int* __restrict__ top1, const float* __restrict__ fold,
    float* __restrict__ outF, u16* __restrict__ outH) {
  __shared__ char Ab[2 * 16384];    // 2 x [256 co][32 ci]
  __shared__ char Bb[2 * 17408];    // 2 x [272 rc][32 ci]
  const int tid = threadIdx.x;
  const int lane = tid & 63;
  const int wid = tid >> 6;
  const int wr = wid >> 1, wc = wid & 1;
  const int orig = blockIdx.x;
  const int swz = (orig & 7) * 64 + (orig >> 3);
  const int ptile = swz & 31, b = swz >> 5;
  const int e = top1[b];

  const char* srcB0 = (const char*)src + ((size_t)b * 4356 + (size_t)ptile * 132) * 512;
  const char* wA0 = (const char*)wt + (size_t)e * 9 * 65536 * 2;

  float4_v acc[8][4];
  #pragma unroll
  for (int m = 0; m < 8; ++m)
    #pragma unroll
    for (int n = 0; n < 4; ++n)
      acc[m][n] = (float4_v){0.f, 0.f, 0.f, 0.f};

  // prologue: stage step 0 (A: chunk0/tap0 -> buf0; B: chunk0 -> buf0)
  stage_tile_1024(wA0, Ab, wid, lane);
  stage_tile_B(srcB0, Bb, wid, lane);
  asm volatile("s_waitcnt vmcnt(0)" ::: "memory");
  __builtin_amdgcn_s_barrier();

  for (int chunk = 0; chunk < 8; ++chunk) {
    #pragma unroll
    for (int tap = 0; tap < 9; ++tap) {
      const int cur = (chunk + tap) & 1;      // == (9*chunk+tap)&1
      // 1. issue prefetches for upcoming steps (targets retired at previous barrier)
      if (!(chunk == 7 && tap == 8)) {
        const int ntap = (tap == 8) ? 0 : tap + 1;
        const int nchunk = (tap == 8) ? chunk + 1 : chunk;
        stage_tile_1024(wA0 + (size_t)ntap * 131072 + nchunk * 64,
                        Ab + (cur ^ 1) * 16384, wid, lane);
      }
      if (tap == 0 && chunk < 7)
        stage_tile_B(srcB0 + (chunk + 1) * 64, Bb + ((chunk + 1) & 1) * 17408, wid, lane);

      // 2. ds_read current fragments
      const char* aB = Ab + cur * 16384;
      const char* bB = Bb + (chunk & 1) * 17408;
      const int kh = tap / 3, kw = tap % 3;
      short8_v bv[4];
      #pragma unroll
      for (int n = 0; n < 4; ++n) {
        int pt = wc * 64 + n * 16 + (lane & 15);
        int rc = ((pt >> 6) + kh) * 66 + (pt & 63) + kw;
        int slot = (lane >> 4) ^ ((rc >> 1) & 3);
        bv[n] = *(const short8_v*)(bB + rc * 64 + slot * 16);
      }
      short8_v av[8];
      #pragma unroll
      for (int m = 0; m < 8; ++m) {
        int cl = wr * 128 + m * 16 + (lane & 15);
        int slot = (lane >> 4) ^ ((cl >> 1) & 3);
        av[m] = *(const short8_v*)(aB + cl * 64 + slot * 16);
      }
      // 3. MFMA cluster (prefetch in flight underneath)
      #pragma unroll
      for (int m = 0; m < 8; ++m)
        #pragma unroll
        for (int n = 0; n < 4; ++n)
          acc[m][n] = __builtin_amdgcn_mfma_f32_16x16x32_bf16(av[m], bv[n], acc[m][n], 0, 0, 0);
      // 4. fence: own prefetch landed, then collective barrier
      asm volatile("s_waitcnt vmcnt(0)" ::: "memory");
      __builtin_amdgcn_s_barrier();
    }
  }

  // epilogue: BN(scale,shift) + ReLU
  const float* fe = fold + (size_t)e * 512;
  #pragma unroll
  for (int m = 0; m < 8; ++m) {
    const int cb = wr * 128 + m * 16 + ((lane >> 4) << 2);  // 4 consecutive co
    float sc0 = fe[(cb + 0) * 2], sh0 = fe[(cb + 0) * 2 + 1];
    float sc1 = fe[(cb + 1) * 2], sh1 = fe[(cb + 1) * 2 + 1];
    float sc2 = fe[(cb + 2) * 2], sh2 = fe[(cb + 2) * 2 + 1];
    float sc3 = fe[(cb + 3) * 2], sh3 = fe[(cb + 3) * 2 + 1];
    #pragma unroll
    for (int n = 0; n < 4; ++n) {
      const int pt = ptile * 128 + wc * 64 + n * 16 + (lane & 15);
      float v0 = fmaxf(acc[m][n][0] * sc0 + sh0, 0.f);
      float v1 = fmaxf(acc[m][n][1] * sc1 + sh1, 0.f);
      float v2 = fmaxf(acc[m][n][2] * sc2 + sh2, 0.f);
      float v3 = fmaxf(acc[m][n][3] * sc3 + sh3, 0.f);
      if (MODE == 1) {
        const size_t rc = (size_t)((pt >> 6) + 1) * 66 + (pt & 63) + 1;
        uint2 pk;
        pk.x = (u32)f2bf(v0) | ((u32)f2bf(v1) << 16);
        pk.y = (u32)f2bf(v2) | ((u32)f2bf(v3) << 16);
        *(uint2*)(outH + ((size_t)b * 4356 + rc) * 256 + cb) = pk;
      } else {
        float* ob = outF + (size_t)b * 1048576;
        ob[(size_t)(cb + 0) * 4096 + pt] = v0;
        ob[(size_t)(cb + 1) * 4096 + pt] = v1;
        ob[(size_t)(cb + 2) * 4096 + pt] = v2;
        ob[(size_t)(cb + 3) * 4096 + pt] = v3;
      }
    }
  }
}

extern "C" void kernel_launch(void* const* d_in, const int* in_sizes, int n_in,
                              void* d_out, int out_size, void* d_ws, size_t ws_size,
                              hipStream_t stream) {
  const float* x    = (const float*)d_in[0];
  const float* meta = (const float*)d_in[1];
  const float* gw1  = (const float*)d_in[2];
  const float* gb1  = (const float*)d_in[3];
  const float* gw2  = (const float*)d_in[4];
  const float* gb2  = (const float*)d_in[5];
  const float* c1w  = (const float*)d_in[6];
  const float* c1b  = (const float*)d_in[7];
  const float* bn1g = (const float*)d_in[8];
  const float* bn1b = (const float*)d_in[9];
  const float* bn1m = (const float*)d_in[10];
  const float* bn1v = (const float*)d_in[11];
  const float* c2w  = (const float*)d_in[12];
  const float* c2b  = (const float*)d_in[13];
  const float* bn2g = (const float*)d_in[14];
  const float* bn2b = (const float*)d_in[15];
  const float* bn2m = (const float*)d_in[16];
  const float* bn2v = (const float*)d_in[17];

  char* ws = (char*)d_ws;
  u16* xpt   = (u16*)(ws);                    // [16][4356][256] bf16 = 35,684,352 B
  u16* hpt   = (u16*)(ws + 35684352);         // same
  u16* w1t   = (u16*)(ws + 71368704);         // [6][9][256][256] bf16 = 7,077,888 B
  u16* w2t   = (u16*)(ws + 78446592);
  float* fold1 = (float*)(ws + 85524480);     // [6][256][2] f32
  float* fold2 = (float*)(ws + 85536768);
  int* top1  = (int*)(ws + 85549056);

  float* outF = (float*)d_out;
  float* loss = outF + 16777216;

  hipLaunchKernelGGL(gate_fold_kernel, dim3(1), dim3(1024), 0, stream,
                     meta, gw1, gb1, gw2, gb2,
                     c1b, bn1g, bn1b, bn1m, bn1v, c2b, bn2g, bn2b, bn2m, bn2v,
                     fold1, fold2, top1, loss);
  hipLaunchKernelGGL(prep_kernel, dim3(5136), dim3(256), 0, stream,
                     c1w, c2w, w1t, w2t, x, xpt, hpt);
  hipLaunchKernelGGL((conv_mfma_kernel<1>), dim3(512), dim3(256), 0, stream,
                     xpt, w1t, top1, fold1, (float*)nullptr, hpt);
  hipLaunchKernelGGL((conv_mfma_kernel<2>), dim3(512), dim3(256), 0, stream,
                     hpt, w2t, top1, fold2, outF, (u16*)nullptr);
}

// Round 16
// 327.595 us; speedup vs baseline: 1.0639x; 1.0639x over previous
//
#include <hip/hip_runtime.h>
#include <hip/hip_bf16.h>

typedef unsigned short u16;
typedef unsigned int u32;
typedef __attribute__((ext_vector_type(8))) short short8_v;   // 8 bf16 (4 VGPRs)
typedef __attribute__((ext_vector_type(4))) float float4_v;

__device__ __forceinline__ u16 f2bf(float f) {
  u32 u = __float_as_uint(f);
  return (u16)((u + 0x7fffu + ((u >> 16) & 1u)) >> 16);   // RNE
}

__device__ __forceinline__ void gl_lds16(const void* g, void* l) {
  __builtin_amdgcn_global_load_lds(
      (const __attribute__((address_space(1))) u32*)g,
      (__attribute__((address_space(3))) u32*)l, 16, 0, 0);
}

// ---- prep_all: [0,3072) wprep | [3072,4096) transpose | [4096,5136) border | 5136 gate+fold ----
__global__ void prep_all_kernel(const float* __restrict__ w1, const float* __restrict__ w2,
                                u16* __restrict__ w1t, u16* __restrict__ w2t,
                                const float* __restrict__ x, u16* __restrict__ xpt,
                                u16* __restrict__ hpt,
                                const float* __restrict__ meta,
                                const float* __restrict__ gw1, const float* __restrict__ gb1,
                                const float* __restrict__ gw2, const float* __restrict__ gb2,
                                const float* __restrict__ c1b, const float* __restrict__ g1,
                                const float* __restrict__ be1, const float* __restrict__ m1,
                                const float* __restrict__ v1,
                                const float* __restrict__ c2b, const float* __restrict__ g2,
                                const float* __restrict__ be2, const float* __restrict__ m2,
                                const float* __restrict__ v2,
                                float* __restrict__ fold1, float* __restrict__ fold2,
                                int* __restrict__ top1, float* __restrict__ loss_out) {
  const int tid = threadIdx.x;   // 256
  const int bx = blockIdx.x;
  __shared__ u16 tile[64 * 258];  // 33,024 B; aliased by wprep (float buf) and gate (probs)

  if (bx < 3072) {
    // weights: [E][co][ci][3][3] f32 -> [E][tap][co][ci] bf16 (LDS-staged transpose)
    float* buf = (float*)tile;
    const int conv = bx >= 1536 ? 1 : 0;
    const int r = bx - (conv ? 1536 : 0);   // e*256 + co
    const int e = r >> 8, co = r & 255;
    const float* src = (conv ? w2 : w1) + (size_t)r * 2304;
    u16* wdst = conv ? w2t : w1t;
    const float4* s4 = (const float4*)src;
    for (int k = tid; k < 576; k += 256) ((float4*)buf)[k] = s4[k];
    __syncthreads();
    for (int j = tid; j < 288; j += 256) {
      int tap = j >> 5, ci0 = (j & 31) * 8;
      u16 v[8];
      #pragma unroll
      for (int i = 0; i < 8; ++i) v[i] = f2bf(buf[(ci0 + i) * 9 + tap]);
      int4 pk;
      pk.x = (int)((u32)v[0] | ((u32)v[1] << 16));
      pk.y = (int)((u32)v[2] | ((u32)v[3] << 16));
      pk.z = (int)((u32)v[4] | ((u32)v[5] << 16));
      pk.w = (int)((u32)v[6] | ((u32)v[7] << 16));
      *(int4*)(wdst + (((size_t)e * 9 + tap) * 256 + co) * 256 + ci0) = pk;
    }
    return;
  }
  if (bx < 4096) {
    // input NCHW f32 -> padded [b][rc=66*66][ci=256] bf16 (interior)
    const int blk = bx - 3072;
    const int b = blk >> 6, r = blk & 63;
    const int cg = tid & 15, ci_g = tid >> 4;
    const float4* xb4 = (const float4*)(x + ((size_t)b * 256) * 4096 + r * 64);
    #pragma unroll
    for (int k = 0; k < 16; ++k) {
      int ci = k * 16 + ci_g;
      float4 v = xb4[(size_t)ci * 1024 + cg];
      tile[(cg * 4 + 0) * 258 + ci] = f2bf(v.x);
      tile[(cg * 4 + 1) * 258 + ci] = f2bf(v.y);
      tile[(cg * 4 + 2) * 258 + ci] = f2bf(v.z);
      tile[(cg * 4 + 3) * 258 + ci] = f2bf(v.w);
    }
    __syncthreads();
    u16* dstb = xpt + ((size_t)b * 4356 + (size_t)(r + 1) * 66 + 1) * 256;
    #pragma unroll
    for (int it = 0; it < 8; ++it) {
      int chunk = it * 256 + tid;
      int cc = chunk >> 5, part = chunk & 31;
      const u32* lp = (const u32*)(tile + cc * 258 + part * 8);
      int4 vv = {(int)lp[0], (int)lp[1], (int)lp[2], (int)lp[3]};
      *(int4*)(dstb + (size_t)cc * 256 + part * 8) = vv;
    }
    return;
  }
  if (bx < 5136) {
    // border zero: 2 bufs x 16 b x 260 rc-rows x 32 parts
    int t = (bx - 4096) * 256 + tid;
    int buf = t / (16 * 260 * 32);
    int r = t % (16 * 260 * 32);
    int b = r / (260 * 32);
    int r2 = r % (260 * 32);
    int idx = r2 >> 5, part = r2 & 31;
    int rc;
    if (idx < 66) rc = idx;                                   // row 0
    else if (idx < 132) rc = 65 * 66 + (idx - 66);            // row 65
    else { int rem = idx - 132; rc = (1 + (rem >> 1)) * 66 + (rem & 1) * 65; }  // cols 0/65
    u16* base = buf ? hpt : xpt;
    int4 z = {0, 0, 0, 0};
    *(int4*)(base + ((size_t)b * 4356 + rc) * 256 + part * 8) = z;
    return;
  }

  // ---- gate (4 waves x 4 samples) + fold + loss, one block ----
  float* probs = (float*)tile;   // [16][6]
  for (int t = tid; t < 3072; t += 256) {
    int conv = t >= 1536 ? 1 : 0;
    int r = t - (conv ? 1536 : 0);
    if (conv == 0) {
      float scale = g1[r] * rsqrtf(v1[r] + 1e-5f);
      float shift = (c1b[r] - m1[r]) * scale + be1[r];
      fold1[r * 2] = scale; fold1[r * 2 + 1] = shift;
    } else {
      float scale = g2[r] * rsqrtf(v2[r] + 1e-5f);
      float shift = (c2b[r] - m2[r]) * scale + be2[r];
      fold2[r * 2] = scale; fold2[r * 2 + 1] = shift;
    }
  }
  const int wid = tid >> 6, lane = tid & 63;
  const float b1a = gb1[lane], b1b = gb1[lane + 64];
  const float w2a0 = gw2[lane * 6 + 0], w2a1 = gw2[lane * 6 + 1], w2a2 = gw2[lane * 6 + 2];
  const float w2a3 = gw2[lane * 6 + 3], w2a4 = gw2[lane * 6 + 4], w2a5 = gw2[lane * 6 + 5];
  const float w2b0 = gw2[(lane + 64) * 6 + 0], w2b1 = gw2[(lane + 64) * 6 + 1], w2b2 = gw2[(lane + 64) * 6 + 2];
  const float w2b3 = gw2[(lane + 64) * 6 + 3], w2b4 = gw2[(lane + 64) * 6 + 4], w2b5 = gw2[(lane + 64) * 6 + 5];
  for (int s = 0; s < 4; ++s) {
    const int b = wid * 4 + s;
    float h0 = b1a, h1 = b1b;
    #pragma unroll
    for (int i = 0; i < 9; ++i) {
      float m = meta[b * 9 + i];
      h0 += m * gw1[i * 128 + lane];
      h1 += m * gw1[i * 128 + lane + 64];
    }
    h0 = fmaxf(h0, 0.f); h1 = fmaxf(h1, 0.f);
    float v[6];
    v[0] = h0 * w2a0 + h1 * w2b0; v[1] = h0 * w2a1 + h1 * w2b1; v[2] = h0 * w2a2 + h1 * w2b2;
    v[3] = h0 * w2a3 + h1 * w2b3; v[4] = h0 * w2a4 + h1 * w2b4; v[5] = h0 * w2a5 + h1 * w2b5;
    #pragma unroll
    for (int off = 32; off >= 1; off >>= 1)
      #pragma unroll
      for (int k = 0; k < 6; ++k) v[k] += __shfl_xor(v[k], off, 64);
    if (lane == 0) {
      float lg[6];
      #pragma unroll
      for (int k = 0; k < 6; ++k) lg[k] = v[k] + gb2[k];
      float m = lg[0];
      for (int k = 1; k < 6; ++k) m = fmaxf(m, lg[k]);
      float sum = 0.f, p[6];
      for (int k = 0; k < 6; ++k) { p[k] = expf(lg[k] - m); sum += p[k]; }
      int best = 0; float bm = p[0];
      for (int k = 1; k < 6; ++k) if (p[k] > bm) { bm = p[k]; best = k; }
      top1[b] = best;
      for (int k = 0; k < 6; ++k) probs[b * 6 + k] = p[k] / sum;
    }
  }
  __syncthreads();
  if (tid == 0) {
    float col[6] = {0, 0, 0, 0, 0, 0}, tot = 0.f;
    for (int bb = 0; bb < 16; ++bb)
      for (int k = 0; k < 6; ++k) col[k] += probs[bb * 6 + k];
    for (int k = 0; k < 6; ++k) tot += col[k];
    float imp[6], mean = 0.f;
    for (int k = 0; k < 6; ++k) { imp[k] = col[k] / (tot + 1e-8f); mean += imp[k]; }
    mean *= (1.f / 6.f);
    float var = 0.f;
    for (int k = 0; k < 6; ++k) { float d = imp[k] - mean; var += d * d; }
    loss_out[0] = sqrtf(var * 0.2f);   // ddof=1 -> /5
  }
}

// ---------------- conv3x3 + BN + ReLU as implicit GEMM (MFMA bf16) ----------------
// R6-proven structure (84 us, MfmaUtil 38%): single-buffered A/B LDS, 2 barriers per
// step, 32 MFMA per step. src: [16][4356][256] bf16 padded-transposed.
// wt: [6][9][256co][256ci] bf16. MODE 1: write hidden back in src layout (interior).
// MODE 2: write f32 NCHW to outF. Tile: 256co x 128pix, 4 waves (2x2), wave tile
// 128x64, acc[8][4]. Grid 512 flat, bijective XCD swizzle (each XCD -> 2 samples ->
// weights L2-resident). LDS 16B-slot swizzle slot=q^((row>>1)&3), inverse-applied at
// global source (linear LDS dest) and at ds_read (rule #21).
template <int MODE>
__global__ __launch_bounds__(256, 2) void conv_mfma_kernel(
    const u16* __restrict__ src, const u16* __restrict__ wt,
    const int* __restrict__ top1, const float* __restrict__ fold,
    float* __restrict__ outF, u16* __restrict__ outH) {
  __shared__ char Ab[16384];    // [256 co][32 ci]
  __shared__ char Bb[17408];    // [272 rc][32 ci]
  const int tid = threadIdx.x;
  const int lane = tid & 63;
  const int wid = tid >> 6;
  const int wr = wid >> 1, wc = wid & 1;
  const int orig = blockIdx.x;
  const int swz = (orig & 7) * 64 + (orig >> 3);
  const int ptile = swz & 31, b = swz >> 5;
  const int e = top1[b];

  const char* srcB0 = (const char*)src + ((size_t)b * 4356 + (size_t)ptile * 132) * 512;
  const char* wA0 = (const char*)wt + (size_t)e * 9 * 65536 * 2;

  float4_v acc[8][4];
  #pragma unroll
  for (int m = 0; m < 8; ++m)
    #pragma unroll
    for (int n = 0; n < 4; ++n)
      acc[m][n] = (float4_v){0.f, 0.f, 0.f, 0.f};

  for (int chunk = 0; chunk < 8; ++chunk) {
    #pragma unroll
    for (int tap = 0; tap < 9; ++tap) {
      __syncthreads();   // previous step's frag reads done before overwrite
      if (tap == 0) {
        // stage B: 272 rows x 32 ci = 1088 16B units (8 rows over-stage, unused)
        const char* sB = srcB0 + chunk * 64;
        const int u0 = wid * 256;
        #pragma unroll
        for (int i = 0; i < 4; ++i) {
          int u = u0 + i * 64 + lane;
          int du = u >> 2;
          int qs = (u & 3) ^ ((u >> 3) & 3);
          gl_lds16(sB + (size_t)du * 512 + qs * 16, Bb + (size_t)(u0 + i * 64) * 16);
        }
        if (wid == 0) {
          int u = 1024 + lane;
          int du = u >> 2;
          int qs = (u & 3) ^ ((u >> 3) & 3);
          gl_lds16(sB + (size_t)du * 512 + qs * 16, Bb + 1024 * 16);
        }
      }
      {
        // stage A for this tap: 256 co x 32 ci = 1024 units, 4 per thread
        const char* sA = wA0 + (size_t)tap * 131072 + chunk * 64;
        const int u0 = wid * 256;
        #pragma unroll
        for (int i = 0; i < 4; ++i) {
          int u = u0 + i * 64 + lane;
          int cl = u >> 2;
          int qs = (u & 3) ^ ((u >> 3) & 3);
          gl_lds16(sA + (size_t)cl * 512 + qs * 16, Ab + (size_t)(u0 + i * 64) * 16);
        }
      }
      __syncthreads();   // compiler drains vmcnt before s_barrier -> staged data visible

      const int kh = tap / 3, kw = tap % 3;
      short8_v bv[4];
      #pragma unroll
      for (int n = 0; n < 4; ++n) {
        int pt = wc * 64 + n * 16 + (lane & 15);
        int rc = ((pt >> 6) + kh) * 66 + (pt & 63) + kw;
        int slot = (lane >> 4) ^ ((rc >> 1) & 3);
        bv[n] = *(const short8_v*)(Bb + rc * 64 + slot * 16);
      }
      #pragma unroll
      for (int m = 0; m < 8; ++m) {
        int cl = wr * 128 + m * 16 + (lane & 15);
        int slot = (lane >> 4) ^ ((cl >> 1) & 3);
        short8_v avm = *(const short8_v*)(Ab + cl * 64 + slot * 16);
        #pragma unroll
        for (int n = 0; n < 4; ++n)
          acc[m][n] = __builtin_amdgcn_mfma_f32_16x16x32_bf16(avm, bv[n], acc[m][n], 0, 0, 0);
      }
    }
  }

  // epilogue: BN(scale,shift) + ReLU
  const float* fe = fold + (size_t)e * 512;
  #pragma unroll
  for (int m = 0; m < 8; ++m) {
    const int cb = wr * 128 + m * 16 + ((lane >> 4) << 2);  // 4 consecutive co
    float sc0 = fe[(cb + 0) * 2], sh0 = fe[(cb + 0) * 2 + 1];
    float sc1 = fe[(cb + 1) * 2], sh1 = fe[(cb + 1) * 2 + 1];
    float sc2 = fe[(cb + 2) * 2], sh2 = fe[(cb + 2) * 2 + 1];
    float sc3 = fe[(cb + 3) * 2], sh3 = fe[(cb + 3) * 2 + 1];
    #pragma unroll
    for (int n = 0; n < 4; ++n) {
      const int pt = ptile * 128 + wc * 64 + n * 16 + (lane & 15);
      float v0 = fmaxf(acc[m][n][0] * sc0 + sh0, 0.f);
      float v1 = fmaxf(acc[m][n][1] * sc1 + sh1, 0.f);
      float v2 = fmaxf(acc[m][n][2] * sc2 + sh2, 0.f);
      float v3 = fmaxf(acc[m][n][3] * sc3 + sh3, 0.f);
      if (MODE == 1) {
        const size_t rc = (size_t)((pt >> 6) + 1) * 66 + (pt & 63) + 1;
        uint2 pk;
        pk.x = (u32)f2bf(v0) | ((u32)f2bf(v1) << 16);
        pk.y = (u32)f2bf(v2) | ((u32)f2bf(v3) << 16);
        *(uint2*)(outH + ((size_t)b * 4356 + rc) * 256 + cb) = pk;
      } else {
        float* ob = outF + (size_t)b * 1048576;
        ob[(size_t)(cb + 0) * 4096 + pt] = v0;
        ob[(size_t)(cb + 1) * 4096 + pt] = v1;
        ob[(size_t)(cb + 2) * 4096 + pt] = v2;
        ob[(size_t)(cb + 3) * 4096 + pt] = v3;
      }
    }
  }
}

extern "C" void kernel_launch(void* const* d_in, const int* in_sizes, int n_in,
                              void* d_out, int out_size, void* d_ws, size_t ws_size,
                              hipStream_t stream) {
  const float* x    = (const float*)d_in[0];
  const float* meta = (const float*)d_in[1];
  const float* gw1  = (const float*)d_in[2];
  const float* gb1  = (const float*)d_in[3];
  const float* gw2  = (const float*)d_in[4];
  const float* gb2  = (const float*)d_in[5];
  const float* c1w  = (const float*)d_in[6];
  const float* c1b  = (const float*)d_in[7];
  const float* bn1g = (const float*)d_in[8];
  const float* bn1b = (const float*)d_in[9];
  const float* bn1m = (const float*)d_in[10];
  const float* bn1v = (const float*)d_in[11];
  const float* c2w  = (const float*)d_in[12];
  const float* c2b  = (const float*)d_in[13];
  const float* bn2g = (const float*)d_in[14];
  const float* bn2b = (const float*)d_in[15];
  const float* bn2m = (const float*)d_in[16];
  const float* bn2v = (const float*)d_in[17];

  char* ws = (char*)d_ws;
  u16* xpt   = (u16*)(ws);                    // [16][4356][256] bf16 = 35,684,352 B
  u16* hpt   = (u16*)(ws + 35684352);         // same
  u16* w1t   = (u16*)(ws + 71368704);         // [6][9][256][256] bf16 = 7,077,888 B
  u16* w2t   = (u16*)(ws + 78446592);
  float* fold1 = (float*)(ws + 85524480);     // [6][256][2] f32
  float* fold2 = (float*)(ws + 85536768);
  int* top1  = (int*)(ws + 85549056);

  float* outF = (float*)d_out;
  float* loss = outF + 16777216;

  hipLaunchKernelGGL(prep_all_kernel, dim3(5137), dim3(256), 0, stream,
                     c1w, c2w, w1t, w2t, x, xpt, hpt,
                     meta, gw1, gb1, gw2, gb2,
                     c1b, bn1g, bn1b, bn1m, bn1v, c2b, bn2g, bn2b, bn2m, bn2v,
                     fold1, fold2, top1, loss);
  hipLaunchKernelGGL((conv_mfma_kernel<1>), dim3(512), dim3(256), 0, stream,
                     xpt, w1t, top1, fold1, (float*)nullptr, hpt);
  hipLaunchKernelGGL((conv_mfma_kernel<2>), dim3(512), dim3(256), 0, stream,
                     hpt, w2t, top1, fold2, outF, (u16*)nullptr);
}